// Round 5
// baseline (159.743 us; speedup 1.0000x reference)
//
#include <hip/hip_runtime.h>
#include <math.h>

// SPLFullLoss: x, ref f32[B=32, N=4096, D=512] -> scalar
//   a = -(1/(N*B)) * sum_rows Sxr/(max(sqrt(Sxx),eps)*max(sqrt(Srr),eps))  (rows along D)
//   b = -(1/(D*B)) * sum_cols Sxr/(max(sqrt(Sxx),eps)*max(sqrt(Srr),eps))  (cols along N)
// R5: device-sequential windows. Per batch b, 256 waves read rows n=wib+256*rr:
// at each step the whole device streams 64 contiguous 512-KiB windows instead
// of 16K scattered 2-KiB streams (HBM row-buffer locality). Body/epilogue = R4.

#define BB 32
#define NN 4096
#define DD 512

static constexpr float EPS = 1e-12f;
static constexpr int BPB   = 64;          // blocks per batch
static constexpr int NWAVE = 4;           // 256 threads
static constexpr int WPB   = BPB * NWAVE; // 256 waves per batch
static constexpr int RPW   = NN / WPB;    // 16 rows per wave
static constexpr int SUB   = 4;           // rows per super-iteration
static constexpr int NSUB  = RPW / SUB;   // 4

// ws layout (floats): cxx[B*D] | crr[B*D] | cxr[B*D] | row_tot[1]
static constexpr size_t WS_CXX = 0;
static constexpr size_t WS_CRR = (size_t)BB * DD;
static constexpr size_t WS_CXR = (size_t)2 * BB * DD;
static constexpr size_t WS_ROW = (size_t)3 * BB * DD;
static constexpr size_t WS_FLOATS = WS_ROW + 1;

__global__ __launch_bounds__(256, 4) void spl_pass1(
    const float* __restrict__ x, const float* __restrict__ r, float* __restrict__ ws) {
  // col exchange buffer, half-D at a time: [wave][m][256] floats = 12 KiB
  __shared__ float lds[NWAVE][3][DD / 2];
  __shared__ float ldsrow[NWAVE];

  const int tid  = threadIdx.x;
  const int wave = tid >> 6;
  const int lane = tid & 63;
  const int blk  = blockIdx.x;
  const int b    = blk >> 6;            // 64 consecutive blocks share a batch
  const int bib  = blk & 63;
  const int wib  = bib * NWAVE + wave;  // wave index within batch, [0,256)

  float cxx[8], crr[8], cxr[8];
#pragma unroll
  for (int j = 0; j < 8; ++j) { cxx[j] = 0.f; crr[j] = 0.f; cxr[j] = 0.f; }
  float rowacc = 0.f;

  const float* xb = x + (size_t)b * NN * DD;
  const float* rb = r + (size_t)b * NN * DD;

#pragma unroll 1
  for (int s = 0; s < NSUB; ++s) {
    // ---- phase 1: issue all 16 loads for 4 rows (rows 256 apart; device-wide
    //      each step covers a contiguous 512-KiB window per (b, array))
    float4 xd[SUB][2], rd[SUB][2];
#pragma unroll
    for (int rr = 0; rr < SUB; ++rr) {
      const int n = wib + (s * SUB + rr) * WPB;
      const float4* xp = (const float4*)(xb + (size_t)n * DD);
      const float4* rp = (const float4*)(rb + (size_t)n * DD);
      xd[rr][0] = xp[lane];
      xd[rr][1] = xp[lane + 64];
      rd[rr][0] = rp[lane];
      rd[rr][1] = rp[lane + 64];
    }

    // ---- phase 2: FMAs (row partials + column accumulators)
    float sxx[SUB], srr[SUB], sxr[SUB];
#pragma unroll
    for (int rr = 0; rr < SUB; ++rr) {
      sxx[rr] = 0.f; srr[rr] = 0.f; sxr[rr] = 0.f;
#pragma unroll
      for (int k = 0; k < 2; ++k) {
        const float xs[4] = {xd[rr][k].x, xd[rr][k].y, xd[rr][k].z, xd[rr][k].w};
        const float rs[4] = {rd[rr][k].x, rd[rr][k].y, rd[rr][k].z, rd[rr][k].w};
#pragma unroll
        for (int j = 0; j < 4; ++j) {
          const float pxx = xs[j] * xs[j];
          const float prr = rs[j] * rs[j];
          const float pxr = xs[j] * rs[j];
          sxx[rr] += pxx; srr[rr] += prr; sxr[rr] += pxr;
          cxx[k * 4 + j] += pxx; crr[k * 4 + j] += prr; cxr[k * 4 + j] += pxr;
        }
      }
    }

    // ---- phase 3: 12 independent butterfly chains, interleaved
#pragma unroll
    for (int off = 1; off < 64; off <<= 1) {
#pragma unroll
      for (int rr = 0; rr < SUB; ++rr) {
        sxx[rr] += __shfl_xor(sxx[rr], off, 64);
        srr[rr] += __shfl_xor(srr[rr], off, 64);
        sxr[rr] += __shfl_xor(sxr[rr], off, 64);
      }
    }
#pragma unroll
    for (int rr = 0; rr < SUB; ++rr) {
      const float nx = fmaxf(sqrtf(sxx[rr]), EPS);
      const float nr = fmaxf(sqrtf(srr[rr]), EPS);
      rowacc += sxr[rr] / (nx * nr);
    }
  }

  if (lane == 0) ldsrow[wave] = rowacc;

  // ---- column exchange, half 0: d in [0,256), reg slots 0..3
  __syncthreads();
  {
    float4* cb = (float4*)&lds[0][0][0];  // [wave*3+m][64] float4s
#pragma unroll
    for (int m = 0; m < 3; ++m) {
      const float* c = (m == 0) ? cxx : (m == 1) ? crr : cxr;
      cb[(wave * 3 + m) * 64 + lane] = make_float4(c[0], c[1], c[2], c[3]);
    }
  }
  __syncthreads();
  for (int i = tid; i < 768; i += 256) {
    const int m = i >> 8;
    const int d = i & 255;
    const float sum = lds[0][m][d] + lds[1][m][d] + lds[2][m][d] + lds[3][m][d];
    atomicAdd(ws + (size_t)m * BB * DD + (size_t)b * DD + d, sum);
  }

  // ---- column exchange, half 1: d in [256,512), reg slots 4..7
  __syncthreads();
  {
    float4* cb = (float4*)&lds[0][0][0];
#pragma unroll
    for (int m = 0; m < 3; ++m) {
      const float* c = (m == 0) ? cxx : (m == 1) ? crr : cxr;
      cb[(wave * 3 + m) * 64 + lane] = make_float4(c[4], c[5], c[6], c[7]);
    }
  }
  __syncthreads();
  for (int i = tid; i < 768; i += 256) {
    const int m = i >> 8;
    const int d = i & 255;
    const float sum = lds[0][m][d] + lds[1][m][d] + lds[2][m][d] + lds[3][m][d];
    atomicAdd(ws + (size_t)m * BB * DD + (size_t)b * DD + 256 + d, sum);
  }

  if (tid == 0) {
    atomicAdd(ws + WS_ROW, ldsrow[0] + ldsrow[1] + ldsrow[2] + ldsrow[3]);
  }
}

__global__ __launch_bounds__(256) void spl_pass2(const float* __restrict__ ws,
                                                 float* __restrict__ out) {
  const int tid = threadIdx.x;
  const float* cxx_g = ws + WS_CXX;
  const float* crr_g = ws + WS_CRR;
  const float* cxr_g = ws + WS_CXR;

  float acc = 0.f;
  for (int i = tid; i < BB * DD; i += 256) {
    const float sxx = cxx_g[i];
    const float srr = crr_g[i];
    const float sxr = cxr_g[i];
    const float nx = fmaxf(sqrtf(sxx), EPS);
    const float nr = fmaxf(sqrtf(srr), EPS);
    acc += sxr / (nx * nr);
  }
#pragma unroll
  for (int off = 1; off < 64; off <<= 1) acc += __shfl_xor(acc, off, 64);

  __shared__ float wsum[4];
  if ((tid & 63) == 0) wsum[tid >> 6] = acc;
  __syncthreads();
  if (tid == 0) {
    const float colsum = wsum[0] + wsum[1] + wsum[2] + wsum[3];
    const float rowsum = ws[WS_ROW];
    const float a = -rowsum / ((float)NN * (float)BB);
    const float b = -colsum / ((float)DD * (float)BB);
    out[0] = a + b;
  }
}

extern "C" void kernel_launch(void* const* d_in, const int* in_sizes, int n_in,
                              void* d_out, int out_size, void* d_ws, size_t ws_size,
                              hipStream_t stream) {
  const float* x = (const float*)d_in[0];
  const float* r = (const float*)d_in[1];
  float* out = (float*)d_out;
  float* ws = (float*)d_ws;

  (void)in_sizes; (void)n_in; (void)out_size; (void)ws_size;

  hipMemsetAsync(ws, 0, WS_FLOATS * sizeof(float), stream);
  spl_pass1<<<BB * BPB, 256, 0, stream>>>(x, r, ws);
  spl_pass2<<<1, 256, 0, stream>>>(ws, out);
}

// Round 7
// 159.163 us; speedup vs baseline: 1.0036x; 1.0036x over previous
//
#include <hip/hip_runtime.h>
#include <math.h>

// SPLFullLoss: x, ref f32[B=32, N=4096, D=512] -> scalar
//   a = -(1/(N*B)) * sum_rows Sxr/(max(sqrt(Sxx),eps)*max(sqrt(Srr),eps))  (rows along D)
//   b = -(1/(D*B)) * sum_cols Sxr/(max(sqrt(Sxx),eps)*max(sqrt(Srr),eps))  (cols along N)
// R7 = R6 fixed: non-temporal loads via clang ext_vector_type (the builtin
// rejects HIP_vector_type). Tests the L1 line-fill-cap theory for the
// invariant 3.4 TB/s delivered read rate seen in R1-R5.

#define BB 32
#define NN 4096
#define DD 512

typedef float f32x4 __attribute__((ext_vector_type(4)));

static constexpr float EPS = 1e-12f;
static constexpr int BPB   = 64;          // blocks per batch
static constexpr int RPB   = NN / BPB;    // 64 rows per block
static constexpr int NWAVE = 4;           // 256 threads
static constexpr int RPW   = RPB / NWAVE; // 16 rows per wave
static constexpr int SUB   = 4;           // rows per super-iteration
static constexpr int NSUB  = RPW / SUB;   // 4

// ws layout (floats): cxx[B*D] | crr[B*D] | cxr[B*D] | row_tot[1]
static constexpr size_t WS_CXX = 0;
static constexpr size_t WS_CRR = (size_t)BB * DD;
static constexpr size_t WS_CXR = (size_t)2 * BB * DD;
static constexpr size_t WS_ROW = (size_t)3 * BB * DD;
static constexpr size_t WS_FLOATS = WS_ROW + 1;

__global__ __launch_bounds__(256, 4) void spl_pass1(
    const float* __restrict__ x, const float* __restrict__ r, float* __restrict__ ws) {
  // col exchange buffer, half-D at a time: [wave][m][256] floats = 12 KiB
  __shared__ float lds[NWAVE][3][DD / 2];
  __shared__ float ldsrow[NWAVE];

  const int tid  = threadIdx.x;
  const int wave = tid >> 6;
  const int lane = tid & 63;
  const int blk  = blockIdx.x;
  const int b    = blk / BPB;
  const int bib  = blk % BPB;
  const int n0   = bib * RPB + wave * RPW;

  float cxx[8], crr[8], cxr[8];
#pragma unroll
  for (int j = 0; j < 8; ++j) { cxx[j] = 0.f; crr[j] = 0.f; cxr[j] = 0.f; }
  float rowacc = 0.f;

  const size_t base = (size_t)b * NN * DD + (size_t)n0 * DD;
  const float* xb = x + base;
  const float* rb = r + base;

#pragma unroll 1
  for (int s = 0; s < NSUB; ++s) {
    // ---- phase 1: issue all 16 non-temporal loads for 4 rows
    f32x4 xd[SUB][2], rd[SUB][2];
#pragma unroll
    for (int rr = 0; rr < SUB; ++rr) {
      const f32x4* xp = (const f32x4*)(xb + (size_t)(s * SUB + rr) * DD);
      const f32x4* rp = (const f32x4*)(rb + (size_t)(s * SUB + rr) * DD);
      xd[rr][0] = __builtin_nontemporal_load(xp + lane);
      xd[rr][1] = __builtin_nontemporal_load(xp + lane + 64);
      rd[rr][0] = __builtin_nontemporal_load(rp + lane);
      rd[rr][1] = __builtin_nontemporal_load(rp + lane + 64);
    }

    // ---- phase 2: FMAs (row partials + column accumulators)
    float sxx[SUB], srr[SUB], sxr[SUB];
#pragma unroll
    for (int rr = 0; rr < SUB; ++rr) {
      sxx[rr] = 0.f; srr[rr] = 0.f; sxr[rr] = 0.f;
#pragma unroll
      for (int k = 0; k < 2; ++k) {
#pragma unroll
        for (int j = 0; j < 4; ++j) {
          const float xv = xd[rr][k][j];
          const float rv = rd[rr][k][j];
          const float pxx = xv * xv;
          const float prr = rv * rv;
          const float pxr = xv * rv;
          sxx[rr] += pxx; srr[rr] += prr; sxr[rr] += pxr;
          cxx[k * 4 + j] += pxx; crr[k * 4 + j] += prr; cxr[k * 4 + j] += pxr;
        }
      }
    }

    // ---- phase 3: 12 independent butterfly chains, interleaved
#pragma unroll
    for (int off = 1; off < 64; off <<= 1) {
#pragma unroll
      for (int rr = 0; rr < SUB; ++rr) {
        sxx[rr] += __shfl_xor(sxx[rr], off, 64);
        srr[rr] += __shfl_xor(srr[rr], off, 64);
        sxr[rr] += __shfl_xor(sxr[rr], off, 64);
      }
    }
#pragma unroll
    for (int rr = 0; rr < SUB; ++rr) {
      const float nx = fmaxf(sqrtf(sxx[rr]), EPS);
      const float nr = fmaxf(sqrtf(srr[rr]), EPS);
      rowacc += sxr[rr] / (nx * nr);
    }
  }

  if (lane == 0) ldsrow[wave] = rowacc;

  // ---- column exchange, half 0: d in [0,256), reg slots 0..3
  __syncthreads();
  {
    float4* cb = (float4*)&lds[0][0][0];  // [wave*3+m][64] float4s
#pragma unroll
    for (int m = 0; m < 3; ++m) {
      const float* c = (m == 0) ? cxx : (m == 1) ? crr : cxr;
      cb[(wave * 3 + m) * 64 + lane] = make_float4(c[0], c[1], c[2], c[3]);
    }
  }
  __syncthreads();
  for (int i = tid; i < 768; i += 256) {
    const int m = i >> 8;
    const int d = i & 255;
    const float sum = lds[0][m][d] + lds[1][m][d] + lds[2][m][d] + lds[3][m][d];
    atomicAdd(ws + (size_t)m * BB * DD + (size_t)b * DD + d, sum);
  }

  // ---- column exchange, half 1: d in [256,512), reg slots 4..7
  __syncthreads();
  {
    float4* cb = (float4*)&lds[0][0][0];
#pragma unroll
    for (int m = 0; m < 3; ++m) {
      const float* c = (m == 0) ? cxx : (m == 1) ? crr : cxr;
      cb[(wave * 3 + m) * 64 + lane] = make_float4(c[4], c[5], c[6], c[7]);
    }
  }
  __syncthreads();
  for (int i = tid; i < 768; i += 256) {
    const int m = i >> 8;
    const int d = i & 255;
    const float sum = lds[0][m][d] + lds[1][m][d] + lds[2][m][d] + lds[3][m][d];
    atomicAdd(ws + (size_t)m * BB * DD + (size_t)b * DD + 256 + d, sum);
  }

  if (tid == 0) {
    atomicAdd(ws + WS_ROW, ldsrow[0] + ldsrow[1] + ldsrow[2] + ldsrow[3]);
  }
}

__global__ __launch_bounds__(256) void spl_pass2(const float* __restrict__ ws,
                                                 float* __restrict__ out) {
  const int tid = threadIdx.x;
  const float* cxx_g = ws + WS_CXX;
  const float* crr_g = ws + WS_CRR;
  const float* cxr_g = ws + WS_CXR;

  float acc = 0.f;
  for (int i = tid; i < BB * DD; i += 256) {
    const float sxx = cxx_g[i];
    const float srr = crr_g[i];
    const float sxr = cxr_g[i];
    const float nx = fmaxf(sqrtf(sxx), EPS);
    const float nr = fmaxf(sqrtf(srr), EPS);
    acc += sxr / (nx * nr);
  }
#pragma unroll
  for (int off = 1; off < 64; off <<= 1) acc += __shfl_xor(acc, off, 64);

  __shared__ float wsum[4];
  if ((tid & 63) == 0) wsum[tid >> 6] = acc;
  __syncthreads();
  if (tid == 0) {
    const float colsum = wsum[0] + wsum[1] + wsum[2] + wsum[3];
    const float rowsum = ws[WS_ROW];
    const float a = -rowsum / ((float)NN * (float)BB);
    const float b = -colsum / ((float)DD * (float)BB);
    out[0] = a + b;
  }
}

extern "C" void kernel_launch(void* const* d_in, const int* in_sizes, int n_in,
                              void* d_out, int out_size, void* d_ws, size_t ws_size,
                              hipStream_t stream) {
  const float* x = (const float*)d_in[0];
  const float* r = (const float*)d_in[1];
  float* out = (float*)d_out;
  float* ws = (float*)d_ws;

  (void)in_sizes; (void)n_in; (void)out_size; (void)ws_size;

  (void)hipMemsetAsync(ws, 0, WS_FLOATS * sizeof(float), stream);
  spl_pass1<<<BB * BPB, 256, 0, stream>>>(x, r, ws);
  spl_pass2<<<1, 256, 0, stream>>>(ws, out);
}

// Round 8
// 150.728 us; speedup vs baseline: 1.0598x; 1.0560x over previous
//
#include <hip/hip_runtime.h>
#include <math.h>

// SPLFullLoss: x, ref f32[B=32, N=4096, D=512] -> scalar
//   a = -(1/(N*B)) * sum_rows Sxr/(max(sqrt(Sxx),eps)*max(sqrt(Srr),eps))  (rows along D)
//   b = -(1/(D*B)) * sum_cols Sxr/(max(sqrt(Sxx),eps)*max(sqrt(Srr),eps))  (cols along N)
// R8: global_load_lds (direct-to-LDS DMA) staging, per-wave double-buffered
// pipeline with counted vmcnt -- tests whether the DMA fill path bypasses the
// ~3.4 TB/s delivered-read cap that pinned R1-R7 (VGPR-return path).

#define BB 32
#define NN 4096
#define DD 512

typedef float f32x4 __attribute__((ext_vector_type(4)));
typedef unsigned int u32;
typedef __attribute__((address_space(1))) const u32 gu32;
typedef __attribute__((address_space(3))) u32 lu32;

static constexpr float EPS = 1e-12f;
static constexpr int BPB   = 64;           // blocks per batch
static constexpr int RPB   = NN / BPB;     // 64 rows per block
static constexpr int NWAVE = 4;            // 256 threads
static constexpr int RPW   = RPB / NWAVE;  // 16 rows per wave
static constexpr int GROUP = 2;            // rows per DMA group
static constexpr int NG    = RPW / GROUP;  // 8 groups
static constexpr int GFLT  = GROUP * DD;   // 1024 floats per array per group

// ws layout (floats): cxx[B*D] | crr[B*D] | cxr[B*D] | row_tot[1]
static constexpr size_t WS_CXX = 0;
static constexpr size_t WS_CRR = (size_t)BB * DD;
static constexpr size_t WS_CXR = (size_t)2 * BB * DD;
static constexpr size_t WS_ROW = (size_t)3 * BB * DD;
static constexpr size_t WS_FLOATS = WS_ROW + 1;

__device__ __forceinline__ void dma16(const float* g, float* l) {
  // one instruction: 64 lanes x 16 B = 1 KiB global -> LDS, lds dest uniform
  __builtin_amdgcn_global_load_lds((gu32*)g, (lu32*)l, 16, 0, 0);
}

__global__ __launch_bounds__(256, 2) void spl_pass1(
    const float* __restrict__ x, const float* __restrict__ r, float* __restrict__ ws) {
  // DMA staging: [wave][buf][array][1024 floats] = 64 KiB
  __shared__ float stg[NWAVE][2][2][GFLT];
  // col exchange buffer, half-D at a time: [wave][m][256] floats = 12 KiB
  __shared__ float lds[NWAVE][3][DD / 2];
  __shared__ float ldsrow[NWAVE];

  const int tid  = threadIdx.x;
  const int wave = tid >> 6;
  const int lane = tid & 63;
  const int blk  = blockIdx.x;
  const int b    = blk / BPB;
  const int bib  = blk % BPB;
  const int n0   = bib * RPB + wave * RPW;

  float cxx[8], crr[8], cxr[8];
#pragma unroll
  for (int j = 0; j < 8; ++j) { cxx[j] = 0.f; crr[j] = 0.f; cxr[j] = 0.f; }
  float rowacc = 0.f;

  const size_t base = (size_t)b * NN * DD + (size_t)n0 * DD;
  const float* xw = x + base;  // wave's 16 contiguous rows = 32 KiB contiguous
  const float* rw = r + base;

  // stage group t (2 rows x 2 arrays = 8 x 1KiB DMA) into buf
  auto stage = [&](int t, int buf) {
    const float* sx = xw + (size_t)t * GFLT + lane * 4;
    const float* sr = rw + (size_t)t * GFLT + lane * 4;
    float* dx = &stg[wave][buf][0][0];
    float* dr = &stg[wave][buf][1][0];
#pragma unroll
    for (int i = 0; i < 4; ++i) {
      dma16(sx + i * 256, dx + i * 256);
      dma16(sr + i * 256, dr + i * 256);
    }
  };

  stage(0, 0);

#pragma unroll 1
  for (int t = 0; t < NG; ++t) {
    const int buf = t & 1;
    if (t + 1 < NG) {
      stage(t + 1, buf ^ 1);
      asm volatile("s_waitcnt vmcnt(8)" ::: "memory");  // group t landed
    } else {
      asm volatile("s_waitcnt vmcnt(0)" ::: "memory");
    }
    __builtin_amdgcn_sched_barrier(0);

    // ---- compute group t from LDS (conflict-free ds_read_b128)
    float sxx[GROUP], srr[GROUP], sxr[GROUP];
#pragma unroll
    for (int rr = 0; rr < GROUP; ++rr) {
      const f32x4* px = (const f32x4*)&stg[wave][buf][0][rr * DD];
      const f32x4* pr = (const f32x4*)&stg[wave][buf][1][rr * DD];
      const f32x4 xv[2] = {px[lane], px[lane + 64]};
      const f32x4 rv[2] = {pr[lane], pr[lane + 64]};
      sxx[rr] = 0.f; srr[rr] = 0.f; sxr[rr] = 0.f;
#pragma unroll
      for (int k = 0; k < 2; ++k) {
#pragma unroll
        for (int j = 0; j < 4; ++j) {
          const float xs = xv[k][j];
          const float rs = rv[k][j];
          const float pxx = xs * xs;
          const float prr = rs * rs;
          const float pxr = xs * rs;
          sxx[rr] += pxx; srr[rr] += prr; sxr[rr] += pxr;
          cxx[k * 4 + j] += pxx; crr[k * 4 + j] += prr; cxr[k * 4 + j] += pxr;
        }
      }
    }
    // 6 independent butterfly chains, interleaved
#pragma unroll
    for (int off = 1; off < 64; off <<= 1) {
#pragma unroll
      for (int rr = 0; rr < GROUP; ++rr) {
        sxx[rr] += __shfl_xor(sxx[rr], off, 64);
        srr[rr] += __shfl_xor(srr[rr], off, 64);
        sxr[rr] += __shfl_xor(sxr[rr], off, 64);
      }
    }
#pragma unroll
    for (int rr = 0; rr < GROUP; ++rr) {
      const float nx = fmaxf(sqrtf(sxx[rr]), EPS);
      const float nr = fmaxf(sqrtf(srr[rr]), EPS);
      rowacc += sxr[rr] / (nx * nr);
    }
  }

  if (lane == 0) ldsrow[wave] = rowacc;

  // ---- column exchange, half 0: d in [0,256), reg slots 0..3
  __syncthreads();
  {
    float4* cb = (float4*)&lds[0][0][0];  // [wave*3+m][64] float4s
#pragma unroll
    for (int m = 0; m < 3; ++m) {
      const float* c = (m == 0) ? cxx : (m == 1) ? crr : cxr;
      cb[(wave * 3 + m) * 64 + lane] = make_float4(c[0], c[1], c[2], c[3]);
    }
  }
  __syncthreads();
  for (int i = tid; i < 768; i += 256) {
    const int m = i >> 8;
    const int d = i & 255;
    const float sum = lds[0][m][d] + lds[1][m][d] + lds[2][m][d] + lds[3][m][d];
    atomicAdd(ws + (size_t)m * BB * DD + (size_t)b * DD + d, sum);
  }

  // ---- column exchange, half 1: d in [256,512), reg slots 4..7
  __syncthreads();
  {
    float4* cb = (float4*)&lds[0][0][0];
#pragma unroll
    for (int m = 0; m < 3; ++m) {
      const float* c = (m == 0) ? cxx : (m == 1) ? crr : cxr;
      cb[(wave * 3 + m) * 64 + lane] = make_float4(c[4], c[5], c[6], c[7]);
    }
  }
  __syncthreads();
  for (int i = tid; i < 768; i += 256) {
    const int m = i >> 8;
    const int d = i & 255;
    const float sum = lds[0][m][d] + lds[1][m][d] + lds[2][m][d] + lds[3][m][d];
    atomicAdd(ws + (size_t)m * BB * DD + (size_t)b * DD + 256 + d, sum);
  }

  if (tid == 0) {
    atomicAdd(ws + WS_ROW, ldsrow[0] + ldsrow[1] + ldsrow[2] + ldsrow[3]);
  }
}

__global__ __launch_bounds__(256) void spl_pass2(const float* __restrict__ ws,
                                                 float* __restrict__ out) {
  const int tid = threadIdx.x;
  const float* cxx_g = ws + WS_CXX;
  const float* crr_g = ws + WS_CRR;
  const float* cxr_g = ws + WS_CXR;

  float acc = 0.f;
  for (int i = tid; i < BB * DD; i += 256) {
    const float sxx = cxx_g[i];
    const float srr = crr_g[i];
    const float sxr = cxr_g[i];
    const float nx = fmaxf(sqrtf(sxx), EPS);
    const float nr = fmaxf(sqrtf(srr), EPS);
    acc += sxr / (nx * nr);
  }
#pragma unroll
  for (int off = 1; off < 64; off <<= 1) acc += __shfl_xor(acc, off, 64);

  __shared__ float wsum[4];
  if ((tid & 63) == 0) wsum[tid >> 6] = acc;
  __syncthreads();
  if (tid == 0) {
    const float colsum = wsum[0] + wsum[1] + wsum[2] + wsum[3];
    const float rowsum = ws[WS_ROW];
    const float a = -rowsum / ((float)NN * (float)BB);
    const float b = -colsum / ((float)DD * (float)BB);
    out[0] = a + b;
  }
}

extern "C" void kernel_launch(void* const* d_in, const int* in_sizes, int n_in,
                              void* d_out, int out_size, void* d_ws, size_t ws_size,
                              hipStream_t stream) {
  const float* x = (const float*)d_in[0];
  const float* r = (const float*)d_in[1];
  float* out = (float*)d_out;
  float* ws = (float*)d_ws;

  (void)in_sizes; (void)n_in; (void)out_size; (void)ws_size;

  (void)hipMemsetAsync(ws, 0, WS_FLOATS * sizeof(float), stream);
  spl_pass1<<<BB * BPB, 256, 0, stream>>>(x, r, ws);
  spl_pass2<<<1, 256, 0, stream>>>(ws, out);
}

// Round 9
// 124.876 us; speedup vs baseline: 1.2792x; 1.2070x over previous
//
#include <hip/hip_runtime.h>
#include <math.h>

// SPLFullLoss: x, ref f32[B=32, N=4096, D=512] -> scalar
//   a = -(1/(N*B)) * sum_rows Sxr/(max(sqrt(Sxx),eps)*max(sqrt(Srr),eps))  (rows along D)
//   b = -(1/(D*B)) * sum_cols Sxr/(max(sqrt(Sxx),eps)*max(sqrt(Srr),eps))  (cols along N)
// R9: R4 streaming body, but NO global atomics and NO memset dispatch:
// pass1 stores column-partials to unique per-block slots (coalesced stores),
// pass2 (256 x 1-wave) reduces across the 64 blocks of each batch,
// pass3 (1 block) combines 256 partials into the scalar.

#define BB 32
#define NN 4096
#define DD 512

static constexpr float EPS = 1e-12f;
static constexpr int BPB   = 64;          // blocks per batch
static constexpr int RPB   = NN / BPB;    // 64 rows per block
static constexpr int NWAVE = 4;           // 256 threads
static constexpr int RPW   = RPB / NWAVE; // 16 rows per wave
static constexpr int SUB   = 4;           // rows per super-iteration
static constexpr int NSUB  = RPW / SUB;   // 4

// ws layout (floats):
//   P[2048 blocks][1600]: [0,512) cxx | [512,1024) crr | [1024,1536) cxr | [1536] rowacc
//   ws2[256] at offset 2048*1600: per-(batch, d-slice) terms (slice 0 also carries row term)
static constexpr size_t S1     = 1600;                 // padded block-slot stride
static constexpr size_t WS_W2  = (size_t)2048 * S1;
static constexpr size_t WS_FLOATS = WS_W2 + 256;

__global__ __launch_bounds__(256, 4) void spl_pass1(
    const float* __restrict__ x, const float* __restrict__ r, float* __restrict__ ws) {
  // col exchange buffer, half-D at a time: [wave][m][256] floats = 12 KiB
  __shared__ float lds[NWAVE][3][DD / 2];
  __shared__ float ldsrow[NWAVE];

  const int tid  = threadIdx.x;
  const int wave = tid >> 6;
  const int lane = tid & 63;
  const int blk  = blockIdx.x;
  const int b    = blk / BPB;
  const int bib  = blk % BPB;
  const int n0   = bib * RPB + wave * RPW;

  float cxx[8], crr[8], cxr[8];
#pragma unroll
  for (int j = 0; j < 8; ++j) { cxx[j] = 0.f; crr[j] = 0.f; cxr[j] = 0.f; }
  float rowacc = 0.f;

  const size_t base = (size_t)b * NN * DD + (size_t)n0 * DD;
  const float* xb = x + base;
  const float* rb = r + base;

#pragma unroll 1
  for (int s = 0; s < NSUB; ++s) {
    // ---- phase 1: issue all 16 loads for 4 rows
    float4 xd[SUB][2], rd[SUB][2];
#pragma unroll
    for (int rr = 0; rr < SUB; ++rr) {
      const float4* xp = (const float4*)(xb + (size_t)(s * SUB + rr) * DD);
      const float4* rp = (const float4*)(rb + (size_t)(s * SUB + rr) * DD);
      xd[rr][0] = xp[lane];
      xd[rr][1] = xp[lane + 64];
      rd[rr][0] = rp[lane];
      rd[rr][1] = rp[lane + 64];
    }

    // ---- phase 2: FMAs (row partials + column accumulators)
    float sxx[SUB], srr[SUB], sxr[SUB];
#pragma unroll
    for (int rr = 0; rr < SUB; ++rr) {
      sxx[rr] = 0.f; srr[rr] = 0.f; sxr[rr] = 0.f;
#pragma unroll
      for (int k = 0; k < 2; ++k) {
        const float xs[4] = {xd[rr][k].x, xd[rr][k].y, xd[rr][k].z, xd[rr][k].w};
        const float rs[4] = {rd[rr][k].x, rd[rr][k].y, rd[rr][k].z, rd[rr][k].w};
#pragma unroll
        for (int j = 0; j < 4; ++j) {
          const float pxx = xs[j] * xs[j];
          const float prr = rs[j] * rs[j];
          const float pxr = xs[j] * rs[j];
          sxx[rr] += pxx; srr[rr] += prr; sxr[rr] += pxr;
          cxx[k * 4 + j] += pxx; crr[k * 4 + j] += prr; cxr[k * 4 + j] += pxr;
        }
      }
    }

    // ---- phase 3: 12 independent butterfly chains, interleaved
#pragma unroll
    for (int off = 1; off < 64; off <<= 1) {
#pragma unroll
      for (int rr = 0; rr < SUB; ++rr) {
        sxx[rr] += __shfl_xor(sxx[rr], off, 64);
        srr[rr] += __shfl_xor(srr[rr], off, 64);
        sxr[rr] += __shfl_xor(sxr[rr], off, 64);
      }
    }
#pragma unroll
    for (int rr = 0; rr < SUB; ++rr) {
      const float nx = fmaxf(sqrtf(sxx[rr]), EPS);
      const float nr = fmaxf(sqrtf(srr[rr]), EPS);
      rowacc += sxr[rr] / (nx * nr);
    }
  }

  if (lane == 0) ldsrow[wave] = rowacc;

  float* P = ws + (size_t)blk * S1;

  // ---- column exchange, half 0: d in [0,256), reg slots 0..3
  __syncthreads();
  {
    float4* cb = (float4*)&lds[0][0][0];  // [wave*3+m][64] float4s
#pragma unroll
    for (int m = 0; m < 3; ++m) {
      const float* c = (m == 0) ? cxx : (m == 1) ? crr : cxr;
      cb[(wave * 3 + m) * 64 + lane] = make_float4(c[0], c[1], c[2], c[3]);
    }
  }
  __syncthreads();
  for (int i = tid; i < 768; i += 256) {
    const int m = i >> 8;
    const int d = i & 255;
    P[m * 512 + d] = lds[0][m][d] + lds[1][m][d] + lds[2][m][d] + lds[3][m][d];
  }

  // ---- column exchange, half 1: d in [256,512), reg slots 4..7
  __syncthreads();
  {
    float4* cb = (float4*)&lds[0][0][0];
#pragma unroll
    for (int m = 0; m < 3; ++m) {
      const float* c = (m == 0) ? cxx : (m == 1) ? crr : cxr;
      cb[(wave * 3 + m) * 64 + lane] = make_float4(c[4], c[5], c[6], c[7]);
    }
  }
  __syncthreads();
  for (int i = tid; i < 768; i += 256) {
    const int m = i >> 8;
    const int d = i & 255;
    P[m * 512 + 256 + d] = lds[0][m][d] + lds[1][m][d] + lds[2][m][d] + lds[3][m][d];
  }

  if (tid == 0) {
    P[1536] = ldsrow[0] + ldsrow[1] + ldsrow[2] + ldsrow[3];
  }
}

// 256 blocks x 64 threads: block g handles batch b=g/8, d-slice (g%8)*64..+64.
// Reduces the 64 per-block partials; slice 0 also reduces the 64 row partials.
__global__ __launch_bounds__(64, 8) void spl_pass2(const float* __restrict__ ws,
                                                   float* __restrict__ ws2) {
  const int lane = threadIdx.x;
  const int g    = blockIdx.x;
  const int b    = g >> 3;
  const int d    = (g & 7) * 64 + lane;

  float sxx = 0.f, srr = 0.f, sxr = 0.f;
  const float* Pb = ws + (size_t)(b * BPB) * S1;
#pragma unroll 4
  for (int bib = 0; bib < BPB; ++bib) {
    const float* P = Pb + (size_t)bib * S1;
    sxx += P[d];
    srr += P[512 + d];
    sxr += P[1024 + d];
  }
  const float nx = fmaxf(sqrtf(sxx), EPS);
  const float nr = fmaxf(sqrtf(srr), EPS);
  float term = sxr / (nx * nr);   // per-d column term
#pragma unroll
  for (int off = 1; off < 64; off <<= 1) term += __shfl_xor(term, off, 64);

  float rterm = 0.f;
  if ((g & 7) == 0) {
    float rv = Pb[(size_t)lane * S1 + 1536];  // one row-partial per lane
#pragma unroll
    for (int off = 1; off < 64; off <<= 1) rv += __shfl_xor(rv, off, 64);
    rterm = rv / (float)NN;
  }

  if (lane == 0) ws2[g] = term / (float)DD + rterm;
}

__global__ __launch_bounds__(256) void spl_pass3(const float* __restrict__ ws2,
                                                 float* __restrict__ out) {
  const int tid = threadIdx.x;
  float acc = ws2[tid];
#pragma unroll
  for (int off = 1; off < 64; off <<= 1) acc += __shfl_xor(acc, off, 64);

  __shared__ float wsum[4];
  if ((tid & 63) == 0) wsum[tid >> 6] = acc;
  __syncthreads();
  if (tid == 0) {
    out[0] = -(wsum[0] + wsum[1] + wsum[2] + wsum[3]) / (float)BB;
  }
}

extern "C" void kernel_launch(void* const* d_in, const int* in_sizes, int n_in,
                              void* d_out, int out_size, void* d_ws, size_t ws_size,
                              hipStream_t stream) {
  const float* x = (const float*)d_in[0];
  const float* r = (const float*)d_in[1];
  float* out = (float*)d_out;
  float* ws = (float*)d_ws;

  (void)in_sizes; (void)n_in; (void)out_size; (void)ws_size;

  spl_pass1<<<BB * BPB, 256, 0, stream>>>(x, r, ws);
  spl_pass2<<<256, 64, 0, stream>>>(ws, ws + WS_W2);
  spl_pass3<<<1, 256, 0, stream>>>(ws + WS_W2, out);
}